// Round 19
// baseline (160.859 us; speedup 1.0000x reference)
//
#include <hip/hip_runtime.h>
#include <hip/hip_bf16.h>
#include <math.h>

// FleetModel forward. Round 19: canvas + layer-0 QKV fused into one kernel
// (qkv engine was xh's only consumer -> drop xh buffer, one fewer dispatch,
// one fewer x round-trip). Attn/engines/readout byte-identical to R18 (best:
// 149.2 µs).
#define NB 128
#define NPOS 652
#define DD 32
#define NH 4
#define NVEH 64
#define ZSTRIDE 162          // 2 + 16*10
#define MROWS (NB*NPOS)      // 83456 = 1304 * 64
#define QSCALE 0.51011784f   // (1/sqrt(8)) * log2(e)

// packed-weight region offsets (f16 elements, per layer)
#define PACK_WO 0
#define PACK_W1 1024
#define PACK_W2 5120
#define PACK_WQ 9216
#define PACK_LAYER 12288

typedef _Float16 half4 __attribute__((ext_vector_type(4)));
typedef _Float16 half8 __attribute__((ext_vector_type(8)));
typedef float float4v __attribute__((ext_vector_type(4)));

__device__ __forceinline__ float4v mfma16(half4 a, half4 b, float4v c) {
  return __builtin_amdgcn_mfma_f32_16x16x16f16(a, b, c, 0, 0, 0);
}

__device__ __forceinline__ float wave_sum64(float v) {
  #pragma unroll
  for (int off = 32; off > 0; off >>= 1) v += __shfl_down(v, off);
  return v;
}

// ------------------------------------------------------------------ pack ----
__global__ void pack_kernel(const float* __restrict__ Wqkv,
                            const float* __restrict__ Wo,
                            const float* __restrict__ W1,
                            const float* __restrict__ W2,
                            _Float16* __restrict__ P)
{
  int L = blockIdx.x;
  int l = threadIdx.x;            // 0..63
  int c = l & 15, g = l >> 4;
  _Float16* PL = P + L*PACK_LAYER;
  const float* WoL = Wo   + L*32*32;
  const float* W1L = W1   + L*32*128;
  const float* W2L = W2   + L*128*32;
  const float* WqL = Wqkv + L*32*96;
  for (int t = 0; t < 2; ++t)
    for (int kp = 0; kp < 2; ++kp)
      for (int jj = 0; jj < 4; ++jj)
        PL[PACK_WO + ((t*2+kp)*64 + l)*4 + jj] =
            (_Float16)WoL[(kp*16 + 4*g + jj)*32 + t*16 + c];
  for (int t = 0; t < 8; ++t)
    for (int kp = 0; kp < 2; ++kp)
      for (int jj = 0; jj < 4; ++jj)
        PL[PACK_W1 + ((t*2+kp)*64 + l)*4 + jj] =
            (_Float16)W1L[(kp*16 + 4*g + jj)*128 + t*16 + c];
  for (int t = 0; t < 2; ++t)
    for (int kp = 0; kp < 8; ++kp)
      for (int jj = 0; jj < 4; ++jj)
        PL[PACK_W2 + ((t*8+kp)*64 + l)*4 + jj] =
            (_Float16)W2L[(kp*16 + 4*g + jj)*32 + t*16 + c];
  for (int t = 0; t < 6; ++t)
    for (int kp = 0; kp < 2; ++kp)
      for (int jj = 0; jj < 4; ++jj) {
        float v = WqL[(kp*16 + 4*g + jj)*96 + t*16 + c];
        if (t < 2) v *= QSCALE;   // fold softmax scale*log2e into Q weights
        PL[PACK_WQ + ((t*2+kp)*64 + l)*4 + jj] = (_Float16)v;
      }
}

// ------------------------------------------------------------ canvas+qkv ----
// 1304 blocks x 256 thr; block owns rows r0 = blk*64 .. +63 (may straddle
// one batch boundary -> both mean-vels computed). Phase 1: canvas -> xf +
// f16 LDS tile [64][34] (stride 17 words: conflict-free frag reads).
// Phase 2: layer-0 QKV MFMA (engine's DO_QKV path, A-frags from LDS).
__global__ __launch_bounds__(256) void canvasqkv_kernel(
    const float* __restrict__ states, const float* __restrict__ road_ctx,
    const float* __restrict__ pos_emb,
    const float* __restrict__ Wp, const float* __restrict__ bp,
    const float* __restrict__ Wv, const float* __restrict__ bv,
    const float* __restrict__ Wh, const float* __restrict__ bh,
    const float* __restrict__ Wc, const float* __restrict__ bc,
    const float* __restrict__ Wflow, const float* __restrict__ bflow,
    const float* __restrict__ Wsig, const float* __restrict__ bsig,
    const _Float16* __restrict__ Pq, const float* __restrict__ bqkv,
    float* __restrict__ xf,
    _Float16* __restrict__ qkh, _Float16* __restrict__ kbh,
    _Float16* __restrict__ vth)
{
  __shared__ _Float16 xls[64][34];
  __shared__ float mvs[2][2];
  const int tid = threadIdx.x;
  const int r0 = blockIdx.x*64;
  const int b0 = r0 / NPOS;
  const int b1 = (r0 + 63) / NPOS;
  // mean velocity for both possible batches (wave 0 -> b0, wave 1 -> b1)
  if (tid < 64) {
    float vx = states[(b0*NVEH + tid)*4 + 2];
    float vy = states[(b0*NVEH + tid)*4 + 3];
    vx = wave_sum64(vx); vy = wave_sum64(vy);
    if (tid == 0) { mvs[0][0] = vx*(1.f/64.f); mvs[0][1] = vy*(1.f/64.f); }
  } else if (tid < 128) {
    int t = tid - 64;
    float vx = states[(b1*NVEH + t)*4 + 2];
    float vy = states[(b1*NVEH + t)*4 + 3];
    vx = wave_sum64(vx); vy = wave_sum64(vy);
    if (t == 0) { mvs[1][0] = vx*(1.f/64.f); mvs[1][1] = vy*(1.f/64.f); }
  }
  __syncthreads();
  // ---- phase 1: canvas (8 contiguous elements per thread)
  {
    const int rl = tid >> 2;               // local row 0..63
    const int row = r0 + rl;
    const int b = row / NPOS, p = row - b*NPOS;
    const float mv0 = mvs[b == b0 ? 0 : 1][0];
    const float mv1 = mvs[b == b0 ? 0 : 1][1];
    const int c0 = (tid & 3)*8;
    #pragma unroll
    for (int j = 0; j < 8; ++j) {
      const int d = c0 + j;
      float val = pos_emb[p*32 + d];
      if (p < 4) {
        val += mv0*Wflow[p*32 + d] + mv1*Wflow[128 + p*32 + d] + bflow[p*32 + d];
      } else {
        int q = p - 4, z = q / ZSTRIDE, r = q % ZSTRIDE;
        if (r == 0) {
          val += Wsig[d] + bsig[d];
        } else if (r >= 2) {
          int vr = r - 2, v = vr / 10, s = vr % 10;
          int n = z*16 + v;
          const float* st = states + (b*NVEH + n)*4;
          if (s == 0) {
            val += st[0]*Wp[d] + st[1]*Wp[32+d] + bp[d];
          } else if (s == 1) {
            val += st[2]*Wv[d] + st[3]*Wv[32+d] + bv[d];
          } else if (s == 2) {
            float sp = fmaxf(sqrtf(st[2]*st[2] + st[3]*st[3]), 0.1f);
            val += (st[2]/sp)*Wh[d] + (st[3]/sp)*Wh[32+d] + bh[d];
          } else if (s == 3) {
            const float* rc = road_ctx + (b*NVEH + n)*4;
            val += rc[0]*Wc[d] + rc[1]*Wc[32+d] + rc[2]*Wc[64+d] + rc[3]*Wc[96+d] + bc[d];
          }
        }
      }
      xf[(size_t)row*32 + d] = val;
      xls[rl][d] = (_Float16)val;
    }
  }
  __syncthreads();
  // ---- phase 2: layer-0 qkv (engine DO_QKV path; A-frags from LDS)
  {
    const int w = tid >> 6, l = tid & 63;
    const int c = l & 15, g = l >> 4;
    const float4v zc = {0.f,0.f,0.f,0.f};
    half4 ax_lo = *(const half4*)&xls[16*w + c][4*g];
    half4 ax_hi = *(const half4*)&xls[16*w + c][16 + 4*g];
    #pragma unroll
    for (int t = 0; t < 6; ++t) {
      float4v qc = mfma16(ax_lo, *(const half4*)(Pq + PACK_WQ + ((t*2+0)*64+l)*4), zc);
      qc = mfma16(ax_hi, *(const half4*)(Pq + PACK_WQ + ((t*2+1)*64+l)*4), qc);
      const int colg = t*16 + c;
      float bb = bqkv[colg] * ((t < 2) ? QSCALE : 1.f);
      const int sec = t >> 1;
      const int hh = (colg & 31) >> 3, dd = colg & 7;
      #pragma unroll
      for (int reg = 0; reg < 4; ++reg) {
        unsigned Rd = (unsigned)(r0 + 16*w + 4*g + reg);
        unsigned bI = Rd / 652u;
        unsigned p  = Rd - bI*652u;
        _Float16 v = (_Float16)(qc[reg] + bb);
        if (sec == 0)      qkh[((size_t)(bI*4+hh)*NPOS + p)*8 + dd] = v;
        else if (sec == 1) kbh[((size_t)(bI*4+hh)*NPOS + p)*8 + dd] = v;
        else               vth[((size_t)(bI*4+hh)*8 + dd)*NPOS + p] = v;
      }
    }
  }
}

// ---------------------------------------------------------------- engine ----
// (frozen — passing, ~15 µs/dispatch). NOTE: phase-2 rows here are r0+4g+reg
// within each wave's 16-row tile (w folded into r0), identical math to above.
template<bool DO_PROJ, bool DO_QKV>
__global__ __launch_bounds__(256) void engine_kernel(
    const _Float16* __restrict__ oh,
    const _Float16* __restrict__ xh,
    float* xf,
    const _Float16* __restrict__ Pm,
    const _Float16* __restrict__ Pq,
    const float* __restrict__ bo,
    const float* __restrict__ g1v, const float* __restrict__ b1v,
    const float* __restrict__ b1f, const float* __restrict__ b2f,
    const float* __restrict__ g2v, const float* __restrict__ b2v,
    const float* __restrict__ bqkv,
    _Float16* __restrict__ qkh, _Float16* __restrict__ kbh,
    _Float16* __restrict__ vth)
{
  __shared__ _Float16 yls[4][16][36];
  __shared__ _Float16 hls[4][16][132];
  const int tid = threadIdx.x;
  const int w = tid >> 6, l = tid & 63;
  const int c = l & 15, g = l >> 4;
  const int r0 = blockIdx.x*64 + w*16;
  const float4v zc = {0.f,0.f,0.f,0.f};

  half4 ax_lo, ax_hi;

  if (DO_PROJ) {
    half4 a_lo = *(const half4*)(oh + (size_t)(r0 + c)*32 + 4*g);
    half4 a_hi = *(const half4*)(oh + (size_t)(r0 + c)*32 + 16 + 4*g);
    float4v c0 = mfma16(a_lo, *(const half4*)(Pm + PACK_WO + (0*64+l)*4), zc);
    c0 = mfma16(a_hi, *(const half4*)(Pm + PACK_WO + (1*64+l)*4), c0);
    float4v c1 = mfma16(a_lo, *(const half4*)(Pm + PACK_WO + (2*64+l)*4), zc);
    c1 = mfma16(a_hi, *(const half4*)(Pm + PACK_WO + (3*64+l)*4), c1);
    float boc0 = bo[c], boc1 = bo[c+16];
    float t0[4], t1[4];
    #pragma unroll
    for (int reg = 0; reg < 4; ++reg) {
      size_t Rd = (size_t)(r0 + 4*g + reg);
      t0[reg] = c0[reg] + boc0 + xf[Rd*32 + c];
      t1[reg] = c1[reg] + boc1 + xf[Rd*32 + c + 16];
    }
    float g1c0 = g1v[c], g1c1 = g1v[c+16], b1c0 = b1v[c], b1c1 = b1v[c+16];
    float y0[4], y1[4];
    #pragma unroll
    for (int reg = 0; reg < 4; ++reg) {
      float s1 = t0[reg] + t1[reg];
      float s2 = t0[reg]*t0[reg] + t1[reg]*t1[reg];
      s1 += __shfl_xor(s1, 1); s1 += __shfl_xor(s1, 2);
      s1 += __shfl_xor(s1, 4); s1 += __shfl_xor(s1, 8);
      s2 += __shfl_xor(s2, 1); s2 += __shfl_xor(s2, 2);
      s2 += __shfl_xor(s2, 4); s2 += __shfl_xor(s2, 8);
      float m = s1*(1.f/32.f);
      float rv = rsqrtf(s2*(1.f/32.f) - m*m + 1e-5f);
      y0[reg] = (t0[reg]-m)*rv*g1c0 + b1c0;
      y1[reg] = (t1[reg]-m)*rv*g1c1 + b1c1;
    }
    #pragma unroll
    for (int reg = 0; reg < 4; ++reg) {
      yls[w][4*g+reg][c]      = (_Float16)y0[reg];
      yls[w][4*g+reg][c + 16] = (_Float16)y1[reg];
    }
    half4 ay_lo = *(const half4*)&yls[w][c][4*g];
    half4 ay_hi = *(const half4*)&yls[w][c][16 + 4*g];
    #pragma unroll
    for (int t = 0; t < 8; ++t) {
      float4v hc = mfma16(ay_lo, *(const half4*)(Pm + PACK_W1 + ((t*2+0)*64+l)*4), zc);
      hc = mfma16(ay_hi, *(const half4*)(Pm + PACK_W1 + ((t*2+1)*64+l)*4), hc);
      float bb = b1f[t*16 + c];
      #pragma unroll
      for (int reg = 0; reg < 4; ++reg)
        hls[w][4*g+reg][t*16 + c] = (_Float16)fmaxf(hc[reg] + bb, 0.f);
    }
    float4v z0 = zc, z1 = zc;
    #pragma unroll
    for (int kp = 0; kp < 8; ++kp) {
      half4 ah = *(const half4*)&hls[w][c][kp*16 + 4*g];
      z0 = mfma16(ah, *(const half4*)(Pm + PACK_W2 + ((0*8+kp)*64+l)*4), z0);
      z1 = mfma16(ah, *(const half4*)(Pm + PACK_W2 + ((1*8+kp)*64+l)*4), z1);
    }
    float b2c0 = b2f[c], b2c1 = b2f[c+16];
    float g2c0 = g2v[c], g2c1 = g2v[c+16], bt0 = b2v[c], bt1 = b2v[c+16];
    float xn0[4], xn1[4];
    #pragma unroll
    for (int reg = 0; reg < 4; ++reg) {
      float u0 = z0[reg] + b2c0 + y0[reg];
      float u1 = z1[reg] + b2c1 + y1[reg];
      float s1 = u0 + u1;
      float s2 = u0*u0 + u1*u1;
      s1 += __shfl_xor(s1, 1); s1 += __shfl_xor(s1, 2);
      s1 += __shfl_xor(s1, 4); s1 += __shfl_xor(s1, 8);
      s2 += __shfl_xor(s2, 1); s2 += __shfl_xor(s2, 2);
      s2 += __shfl_xor(s2, 4); s2 += __shfl_xor(s2, 8);
      float m = s1*(1.f/32.f);
      float rv = rsqrtf(s2*(1.f/32.f) - m*m + 1e-5f);
      xn0[reg] = (u0-m)*rv*g2c0 + bt0;
      xn1[reg] = (u1-m)*rv*g2c1 + bt1;
    }
    #pragma unroll
    for (int reg = 0; reg < 4; ++reg) {
      size_t Rd = (size_t)(r0 + 4*g + reg);
      xf[Rd*32 + c]      = xn0[reg];
      xf[Rd*32 + c + 16] = xn1[reg];
    }
    if (DO_QKV) {
      #pragma unroll
      for (int reg = 0; reg < 4; ++reg) {
        yls[w][4*g+reg][c]      = (_Float16)xn0[reg];
        yls[w][4*g+reg][c + 16] = (_Float16)xn1[reg];
      }
      ax_lo = *(const half4*)&yls[w][c][4*g];
      ax_hi = *(const half4*)&yls[w][c][16 + 4*g];
    }
  } else if (DO_QKV) {
    ax_lo = *(const half4*)(xh + (size_t)(r0 + c)*32 + 4*g);
    ax_hi = *(const half4*)(xh + (size_t)(r0 + c)*32 + 16 + 4*g);
  }

  if (DO_QKV) {
    #pragma unroll
    for (int t = 0; t < 6; ++t) {
      float4v qc = mfma16(ax_lo, *(const half4*)(Pq + PACK_WQ + ((t*2+0)*64+l)*4), zc);
      qc = mfma16(ax_hi, *(const half4*)(Pq + PACK_WQ + ((t*2+1)*64+l)*4), qc);
      const int colg = t*16 + c;
      float bb = bqkv[colg] * ((t < 2) ? QSCALE : 1.f);
      const int sec = t >> 1;
      const int hh = (colg & 31) >> 3, dd = colg & 7;
      #pragma unroll
      for (int reg = 0; reg < 4; ++reg) {
        unsigned Rd = (unsigned)(r0 + 4*g + reg);
        unsigned bI = Rd / 652u;
        unsigned p  = Rd - bI*652u;
        _Float16 v = (_Float16)(qc[reg] + bb);
        if (sec == 0)      qkh[((size_t)(bI*4+hh)*NPOS + p)*8 + dd] = v;
        else if (sec == 1) kbh[((size_t)(bI*4+hh)*NPOS + p)*8 + dd] = v;
        else               vth[((size_t)(bI*4+hh)*8 + dd)*NPOS + p] = v;
      }
    }
  }
}

// ------------------------------------------------------------------ attn ----
// (frozen — R18: half-major remap, dual sweep + tail, lean K LDS, ones-row den)
#define VSTR 670
__global__ __launch_bounds__(512) void attn_kernel(
    const _Float16* __restrict__ qkh, const _Float16* __restrict__ kbh,
    const _Float16* __restrict__ vth, _Float16* __restrict__ oh)
{
  __shared__ _Float16 Klds[656*8];       // 10.5 KB
  __shared__ _Float16 VTlds[16*VSTR];    // 20.9 KB
  int blk = blockIdx.x;
  int bh = blk & 511, half = blk >> 9;   // half-major remap (same-XCD pairs)
  int b = bh >> 2, h = bh & 3;
  int tid = threadIdx.x;
  const half4 z4 = {0,0,0,0};
  const half4 o4 = {(_Float16)1.f,(_Float16)1.f,(_Float16)1.f,(_Float16)1.f};
  for (int r = tid; r < 656; r += 512) {
    half8 kv = {0,0,0,0,0,0,0,0};
    if (r < NPOS) kv = *(const half8*)(kbh + ((size_t)bh*NPOS + r)*8);
    *(half8*)(Klds + r*8) = kv;
  }
  for (int i = tid; i < 16*167; i += 512) {
    int d = i / 167, kc = (i % 167)*4;
    half4 v = z4;
    if (kc < 652) {
      if (d < 8)       v = *(const half4*)(vth + ((size_t)bh*8 + d)*NPOS + kc);
      else if (d == 8) v = o4;
    }
    *(half4*)(VTlds + d*VSTR + kc) = v;
  }
  __syncthreads();

  int wave = tid >> 6, lane = tid & 63;
  int q16 = lane & 15;
  int kg  = lane >> 4;
  const int denl = (lane & 48) | 8;
  const float4v zc = {0.f,0.f,0.f,0.f};
  const int lo = half ? 21 : 0;
  const int span = half ? 20 : 21;

  // ---- sweep 1: dual chain
  {
    const int qtA = lo + wave, qtB = lo + wave + 8;
    int qrcA = qtA*16 + q16;
    int qrowB = qtB*16 + q16;
    int qrcB = qrowB < NPOS ? qrowB : NPOS-1;
    half4 qfA = z4, qfB = z4;
    if (kg < 2) {
      qfA = *(const half4*)(qkh + ((size_t)bh*NPOS + qrcA)*8 + kg*4);
      qfB = *(const half4*)(qkh + ((size_t)bh*NPOS + qrcB)*8 + kg*4);
    }
    float4v oA = zc, oB = zc;
    for (int kt = 0; kt < 41; ++kt) {
      half4 kf = z4;
      if (kg < 2)
        kf = *(const half4*)(Klds + (kt*16 + q16)*8 + kg*4);
      half4 vf = *(const half4*)(VTlds + q16*VSTR + kt*16 + (kg << 2));
      float4v sA = __builtin_amdgcn_mfma_f32_16x16x16f16(kf, qfA, zc, 0, 0, 0);
      float4v sB = __builtin_amdgcn_mfma_f32_16x16x16f16(kf, qfB, zc, 0, 0, 0);
      half4 pfA, pfB;
      pfA[0] = (_Float16)__builtin_amdgcn_exp2f(sA[0]);
      pfA[1] = (_Float16)__builtin_amdgcn_exp2f(sA[1]);
      pfA[2] = (_Float16)__builtin_amdgcn_exp2f(sA[2]);
      pfA[3] = (_Float16)__builtin_amdgcn_exp2f(sA[3]);
      pfB[0] = (_Float16)__builtin_amdgcn_exp2f(sB[0]);
      pfB[1] = (_Float16)__builtin_amdgcn_exp2f(sB[1]);
      pfB[2] = (_Float16)__builtin_amdgcn_exp2f(sB[2]);
      pfB[3] = (_Float16)__builtin_amdgcn_exp2f(sB[3]);
      oA = __builtin_amdgcn_mfma_f32_16x16x16f16(pfA, vf, oA, 0, 0, 0);
      oB = __builtin_amdgcn_mfma_f32_16x16x16f16(pfB, vf, oB, 0, 0, 0);
    }
    float dqA[4], dqB[4];
    #pragma unroll
    for (int reg = 0; reg < 4; ++reg) {
      dqA[reg] = __shfl(oA[reg], denl);
      dqB[reg] = __shfl(oB[reg], denl);
    }
    if (q16 < 8) {
      #pragma unroll
      for (int reg = 0; reg < 4; ++reg) {
        int qoA = qtA*16 + 4*kg + reg;
        oh[((size_t)(b*NPOS + qoA))*32 + h*8 + q16] = (_Float16)(oA[reg] / dqA[reg]);
        int qoB = qtB*16 + 4*kg + reg;
        if (qoB < NPOS)
          oh[((size_t)(b*NPOS + qoB))*32 + h*8 + q16] = (_Float16)(oB[reg] / dqB[reg]);
      }
    }
  }
  // ---- sweep 2: single-chain tail
  if (wave < span - 16) {
    const int qt = lo + 16 + wave;
    int qrow = qt*16 + q16;
    int qrc = qrow < NPOS ? qrow : NPOS-1;
    half4 qf = z4;
    if (kg < 2)
      qf = *(const half4*)(qkh + ((size_t)bh*NPOS + qrc)*8 + kg*4);
    float4v o = zc;
    for (int kt = 0; kt < 41; ++kt) {
      half4 kf = z4;
      if (kg < 2)
        kf = *(const half4*)(Klds + (kt*16 + q16)*8 + kg*4);
      half4 vf = *(const half4*)(VTlds + q16*VSTR + kt*16 + (kg << 2));
      float4v s = __builtin_amdgcn_mfma_f32_16x16x16f16(kf, qf, zc, 0, 0, 0);
      half4 pf;
      pf[0] = (_Float16)__builtin_amdgcn_exp2f(s[0]);
      pf[1] = (_Float16)__builtin_amdgcn_exp2f(s[1]);
      pf[2] = (_Float16)__builtin_amdgcn_exp2f(s[2]);
      pf[3] = (_Float16)__builtin_amdgcn_exp2f(s[3]);
      o = __builtin_amdgcn_mfma_f32_16x16x16f16(pf, vf, o, 0, 0, 0);
    }
    float dq[4];
    #pragma unroll
    for (int reg = 0; reg < 4; ++reg)
      dq[reg] = __shfl(o[reg], denl);
    if (q16 < 8) {
      #pragma unroll
      for (int reg = 0; reg < 4; ++reg) {
        int qo = qt*16 + 4*kg + reg;
        if (qo < NPOS)
          oh[((size_t)(b*NPOS + qo))*32 + h*8 + q16] = (_Float16)(o[reg] / dq[reg]);
      }
    }
  }
}

// --------------------------------------------------------------- readout ----
__global__ __launch_bounds__(256) void readout_kernel(
    const float* __restrict__ x,
    const float* __restrict__ Wtraj, const float* __restrict__ btraj,
    const float* __restrict__ Wint, const float* __restrict__ bint,
    float* __restrict__ dout)
{
  int idx = blockIdx.x*256 + threadIdx.x;
  if (idx >= NB*NVEH) return;
  int b = idx >> 6, n = idx & 63;
  int z = n >> 4, v = n & 15;
  int base = 4 + z*ZSTRIDE + 2 + v*10;
  float acc[16];
  #pragma unroll
  for (int i = 0; i < 16; ++i) acc[i] = btraj[i];
  #pragma unroll
  for (int t = 0; t < 4; ++t) {
    const float* xr = x + ((size_t)(b*NPOS + base + 6 + t))*32;
    #pragma unroll
    for (int k = 0; k < 32; ++k) {
      float xv = xr[k];
      const float* wr = Wtraj + (t*32 + k)*16;
      #pragma unroll
      for (int i = 0; i < 16; ++i) acc[i] += xv*wr[i];
    }
  }
  float* to = dout + (size_t)idx*16;
  #pragma unroll
  for (int i = 0; i < 16; ++i) to[i] = acc[i];
  float ai[8];
  #pragma unroll
  for (int j = 0; j < 8; ++j) ai[j] = bint[j];
  #pragma unroll
  for (int t = 0; t < 2; ++t) {
    const float* xr = x + ((size_t)(b*NPOS + base + 4 + t))*32;
    #pragma unroll
    for (int k = 0; k < 32; ++k) {
      float xv = xr[k];
      const float* wr = Wint + (t*32 + k)*8;
      #pragma unroll
      for (int j = 0; j < 8; ++j) ai[j] += xv*wr[j];
    }
  }
  float* io = dout + 131072 + (size_t)idx*8;
  #pragma unroll
  for (int j = 0; j < 8; ++j) io[j] = ai[j];
}

// ---------------------------------------------------------------- launch ----
extern "C" void kernel_launch(void* const* d_in, const int* in_sizes, int n_in,
                              void* d_out, int out_size, void* d_ws, size_t ws_size,
                              hipStream_t stream)
{
  const float* states  = (const float*)d_in[0];
  const float* road_ctx= (const float*)d_in[1];
  const float* pos_emb = (const float*)d_in[2];
  const float* Wp    = (const float*)d_in[4];  const float* bp    = (const float*)d_in[5];
  const float* Wv    = (const float*)d_in[6];  const float* bv    = (const float*)d_in[7];
  const float* Wh    = (const float*)d_in[8];  const float* bh    = (const float*)d_in[9];
  const float* Wc    = (const float*)d_in[10]; const float* bc    = (const float*)d_in[11];
  const float* Wflow = (const float*)d_in[12]; const float* bflow = (const float*)d_in[13];
  const float* Wsig  = (const float*)d_in[14]; const float* bsig  = (const float*)d_in[15];
  const float* Wtraj = (const float*)d_in[16]; const float* btraj = (const float*)d_in[17];
  const float* Wint  = (const float*)d_in[18]; const float* bint  = (const float*)d_in[19];
  const float* Wqkv  = (const float*)d_in[20]; const float* bqkv  = (const float*)d_in[21];
  const float* Wo    = (const float*)d_in[22]; const float* bo    = (const float*)d_in[23];
  const float* g1    = (const float*)d_in[24]; const float* b1ln  = (const float*)d_in[25];
  const float* W1    = (const float*)d_in[26]; const float* b1    = (const float*)d_in[27];
  const float* W2    = (const float*)d_in[28]; const float* b2    = (const float*)d_in[29];
  const float* g2    = (const float*)d_in[30]; const float* b2ln  = (const float*)d_in[31];

  // workspace layout (xh eliminated)
  float*     xf  = (float*)d_ws;                           // 10.7 MB fp32
  _Float16*  oh  = (_Float16*)(xf + (size_t)MROWS*32);     // 5.3 MB f16
  _Float16*  qkh = oh  + (size_t)MROWS*32;                 // 5.3 MB
  _Float16*  kbh = qkh + (size_t)512*NPOS*8;               // 5.3 MB
  _Float16*  vth = kbh + (size_t)512*NPOS*8;               // 5.3 MB
  _Float16*  P   = vth + (size_t)512*NPOS*8;               // 48 KB packed W

  const int eBlocks = MROWS/64;   // 1304

  pack_kernel<<<2, 64, 0, stream>>>(Wqkv, Wo, W1, W2, P);

  // canvas + layer-0 qkv fused
  canvasqkv_kernel<<<eBlocks, 256, 0, stream>>>(
      states, road_ctx, pos_emb,
      Wp, bp, Wv, bv, Wh, bh, Wc, bc, Wflow, bflow, Wsig, bsig,
      P, bqkv, xf, qkh, kbh, vth);

  attn_kernel<<<NB*NH*2, 512, 0, stream>>>(qkh, kbh, vth, oh);

  // layer 0 proj+LN+FFN+LN (Pm = layer 0) fused with layer 1 qkv (Pq = layer 1)
  engine_kernel<true,true><<<eBlocks, 256, 0, stream>>>(
      oh, nullptr, xf, P, P + PACK_LAYER,
      bo, g1, b1ln, b1, b2, g2, b2ln,
      bqkv + 96, qkh, kbh, vth);

  attn_kernel<<<NB*NH*2, 512, 0, stream>>>(qkh, kbh, vth, oh);

  // layer 1 proj+LN+FFN+LN (Pm = layer 1)
  engine_kernel<true,false><<<eBlocks, 256, 0, stream>>>(
      oh, nullptr, xf, P + PACK_LAYER, nullptr,
      bo + 32, g1 + 32, b1ln + 32, b1 + 128, b2 + 32, g2 + 32, b2ln + 32,
      nullptr, nullptr, nullptr, nullptr);

  readout_kernel<<<(NB*NVEH + 255)/256, 256, 0, stream>>>(
      xf, Wtraj, btraj, Wint, bint, (float*)d_out);
}

// Round 20
// 148.731 us; speedup vs baseline: 1.0815x; 1.0815x over previous
//
#include <hip/hip_runtime.h>
#include <hip/hip_bf16.h>
#include <math.h>

// FleetModel forward. Round 20: REVERT to R18 exact (measured best 149.2 µs).
// R19's canvas+qkv fusion regressed (divergent fused canvas phase cost more
// than the saved dispatch gap). This is the converged configuration:
// - canvas: 1024 blocks, coalesced, fp32 xf + f16 xh
// - engines: MFMA f16, packed weights, wave-private LDS, no barriers
// - attn: 512 thr, q-split x2 half-major (same-XCD pairs), dual sweep +
//   tail, lean K LDS (8 dims), ones-row denominator, natural VGPR
#define NB 128
#define NPOS 652
#define DD 32
#define NH 4
#define NVEH 64
#define ZSTRIDE 162          // 2 + 16*10
#define MROWS (NB*NPOS)      // 83456 = 1304 * 64
#define QSCALE 0.51011784f   // (1/sqrt(8)) * log2(e)

// packed-weight region offsets (f16 elements, per layer)
#define PACK_WO 0
#define PACK_W1 1024
#define PACK_W2 5120
#define PACK_WQ 9216
#define PACK_LAYER 12288

typedef _Float16 half4 __attribute__((ext_vector_type(4)));
typedef _Float16 half8 __attribute__((ext_vector_type(8)));
typedef float float4v __attribute__((ext_vector_type(4)));

__device__ __forceinline__ float4v mfma16(half4 a, half4 b, float4v c) {
  return __builtin_amdgcn_mfma_f32_16x16x16f16(a, b, c, 0, 0, 0);
}

__device__ __forceinline__ float wave_sum64(float v) {
  #pragma unroll
  for (int off = 32; off > 0; off >>= 1) v += __shfl_down(v, off);
  return v;
}

// ---------------------------------------------------------------- canvas ----
__global__ __launch_bounds__(256) void canvas_kernel(
    const float* __restrict__ states, const float* __restrict__ road_ctx,
    const float* __restrict__ pos_emb,
    const float* __restrict__ Wp, const float* __restrict__ bp,
    const float* __restrict__ Wv, const float* __restrict__ bv,
    const float* __restrict__ Wh, const float* __restrict__ bh,
    const float* __restrict__ Wc, const float* __restrict__ bc,
    const float* __restrict__ Wflow, const float* __restrict__ bflow,
    const float* __restrict__ Wsig, const float* __restrict__ bsig,
    float* __restrict__ x, _Float16* __restrict__ xh)
{
  int blk = blockIdx.x;
  int b = blk >> 3, chunk = blk & 7;
  int tid = threadIdx.x;
  __shared__ float mvs[2];
  if (tid < 64) {
    float vx = states[(b*NVEH + tid)*4 + 2];
    float vy = states[(b*NVEH + tid)*4 + 3];
    vx = wave_sum64(vx); vy = wave_sum64(vy);
    if (tid == 0) { mvs[0] = vx * (1.f/64.f); mvs[1] = vy * (1.f/64.f); }
  }
  __syncthreads();
  float mv0 = mvs[0], mv1 = mvs[1];
  const int i0 = chunk*2608, i1 = i0 + 2608;   // 2608 = 652*32/8
  for (int i = i0 + tid; i < i1; i += 256) {
    int p = i >> 5, d = i & 31;
    float val = pos_emb[i];
    if (p < 4) {
      val += mv0*Wflow[p*32 + d] + mv1*Wflow[128 + p*32 + d] + bflow[p*32 + d];
    } else {
      int q = p - 4, z = q / ZSTRIDE, r = q % ZSTRIDE;
      if (r == 0) {
        val += Wsig[d] + bsig[d];
      } else if (r >= 2) {
        int vr = r - 2, v = vr / 10, s = vr % 10;
        int n = z*16 + v;
        const float* st = states + (b*NVEH + n)*4;
        if (s == 0) {
          val += st[0]*Wp[d] + st[1]*Wp[32+d] + bp[d];
        } else if (s == 1) {
          val += st[2]*Wv[d] + st[3]*Wv[32+d] + bv[d];
        } else if (s == 2) {
          float sp = fmaxf(sqrtf(st[2]*st[2] + st[3]*st[3]), 0.1f);
          val += (st[2]/sp)*Wh[d] + (st[3]/sp)*Wh[32+d] + bh[d];
        } else if (s == 3) {
          const float* rc = road_ctx + (b*NVEH + n)*4;
          val += rc[0]*Wc[d] + rc[1]*Wc[32+d] + rc[2]*Wc[64+d] + rc[3]*Wc[96+d] + bc[d];
        }
      }
    }
    x[(size_t)b*NPOS*DD + i] = val;
    xh[(size_t)b*NPOS*DD + i] = (_Float16)val;
  }
}

// ------------------------------------------------------------------ pack ----
__global__ void pack_kernel(const float* __restrict__ Wqkv,
                            const float* __restrict__ Wo,
                            const float* __restrict__ W1,
                            const float* __restrict__ W2,
                            _Float16* __restrict__ P)
{
  int L = blockIdx.x;
  int l = threadIdx.x;            // 0..63
  int c = l & 15, g = l >> 4;
  _Float16* PL = P + L*PACK_LAYER;
  const float* WoL = Wo   + L*32*32;
  const float* W1L = W1   + L*32*128;
  const float* W2L = W2   + L*128*32;
  const float* WqL = Wqkv + L*32*96;
  for (int t = 0; t < 2; ++t)
    for (int kp = 0; kp < 2; ++kp)
      for (int jj = 0; jj < 4; ++jj)
        PL[PACK_WO + ((t*2+kp)*64 + l)*4 + jj] =
            (_Float16)WoL[(kp*16 + 4*g + jj)*32 + t*16 + c];
  for (int t = 0; t < 8; ++t)
    for (int kp = 0; kp < 2; ++kp)
      for (int jj = 0; jj < 4; ++jj)
        PL[PACK_W1 + ((t*2+kp)*64 + l)*4 + jj] =
            (_Float16)W1L[(kp*16 + 4*g + jj)*128 + t*16 + c];
  for (int t = 0; t < 2; ++t)
    for (int kp = 0; kp < 8; ++kp)
      for (int jj = 0; jj < 4; ++jj)
        PL[PACK_W2 + ((t*8+kp)*64 + l)*4 + jj] =
            (_Float16)W2L[(kp*16 + 4*g + jj)*32 + t*16 + c];
  for (int t = 0; t < 6; ++t)
    for (int kp = 0; kp < 2; ++kp)
      for (int jj = 0; jj < 4; ++jj) {
        float v = WqL[(kp*16 + 4*g + jj)*96 + t*16 + c];
        if (t < 2) v *= QSCALE;   // fold softmax scale*log2e into Q weights
        PL[PACK_WQ + ((t*2+kp)*64 + l)*4 + jj] = (_Float16)v;
      }
}

// ---------------------------------------------------------------- engine ----
template<bool DO_PROJ, bool DO_QKV>
__global__ __launch_bounds__(256) void engine_kernel(
    const _Float16* __restrict__ oh,
    const _Float16* __restrict__ xh,
    float* xf,
    const _Float16* __restrict__ Pm,
    const _Float16* __restrict__ Pq,
    const float* __restrict__ bo,
    const float* __restrict__ g1v, const float* __restrict__ b1v,
    const float* __restrict__ b1f, const float* __restrict__ b2f,
    const float* __restrict__ g2v, const float* __restrict__ b2v,
    const float* __restrict__ bqkv,
    _Float16* __restrict__ qkh, _Float16* __restrict__ kbh,
    _Float16* __restrict__ vth)
{
  __shared__ _Float16 yls[4][16][36];
  __shared__ _Float16 hls[4][16][132];
  const int tid = threadIdx.x;
  const int w = tid >> 6, l = tid & 63;
  const int c = l & 15, g = l >> 4;
  const int r0 = blockIdx.x*64 + w*16;
  const float4v zc = {0.f,0.f,0.f,0.f};

  half4 ax_lo, ax_hi;

  if (DO_PROJ) {
    half4 a_lo = *(const half4*)(oh + (size_t)(r0 + c)*32 + 4*g);
    half4 a_hi = *(const half4*)(oh + (size_t)(r0 + c)*32 + 16 + 4*g);
    float4v c0 = mfma16(a_lo, *(const half4*)(Pm + PACK_WO + (0*64+l)*4), zc);
    c0 = mfma16(a_hi, *(const half4*)(Pm + PACK_WO + (1*64+l)*4), c0);
    float4v c1 = mfma16(a_lo, *(const half4*)(Pm + PACK_WO + (2*64+l)*4), zc);
    c1 = mfma16(a_hi, *(const half4*)(Pm + PACK_WO + (3*64+l)*4), c1);
    float boc0 = bo[c], boc1 = bo[c+16];
    float t0[4], t1[4];
    #pragma unroll
    for (int reg = 0; reg < 4; ++reg) {
      size_t Rd = (size_t)(r0 + 4*g + reg);
      t0[reg] = c0[reg] + boc0 + xf[Rd*32 + c];
      t1[reg] = c1[reg] + boc1 + xf[Rd*32 + c + 16];
    }
    float g1c0 = g1v[c], g1c1 = g1v[c+16], b1c0 = b1v[c], b1c1 = b1v[c+16];
    float y0[4], y1[4];
    #pragma unroll
    for (int reg = 0; reg < 4; ++reg) {
      float s1 = t0[reg] + t1[reg];
      float s2 = t0[reg]*t0[reg] + t1[reg]*t1[reg];
      s1 += __shfl_xor(s1, 1); s1 += __shfl_xor(s1, 2);
      s1 += __shfl_xor(s1, 4); s1 += __shfl_xor(s1, 8);
      s2 += __shfl_xor(s2, 1); s2 += __shfl_xor(s2, 2);
      s2 += __shfl_xor(s2, 4); s2 += __shfl_xor(s2, 8);
      float m = s1*(1.f/32.f);
      float rv = rsqrtf(s2*(1.f/32.f) - m*m + 1e-5f);
      y0[reg] = (t0[reg]-m)*rv*g1c0 + b1c0;
      y1[reg] = (t1[reg]-m)*rv*g1c1 + b1c1;
    }
    #pragma unroll
    for (int reg = 0; reg < 4; ++reg) {
      yls[w][4*g+reg][c]      = (_Float16)y0[reg];
      yls[w][4*g+reg][c + 16] = (_Float16)y1[reg];
    }
    half4 ay_lo = *(const half4*)&yls[w][c][4*g];
    half4 ay_hi = *(const half4*)&yls[w][c][16 + 4*g];
    #pragma unroll
    for (int t = 0; t < 8; ++t) {
      float4v hc = mfma16(ay_lo, *(const half4*)(Pm + PACK_W1 + ((t*2+0)*64+l)*4), zc);
      hc = mfma16(ay_hi, *(const half4*)(Pm + PACK_W1 + ((t*2+1)*64+l)*4), hc);
      float bb = b1f[t*16 + c];
      #pragma unroll
      for (int reg = 0; reg < 4; ++reg)
        hls[w][4*g+reg][t*16 + c] = (_Float16)fmaxf(hc[reg] + bb, 0.f);
    }
    float4v z0 = zc, z1 = zc;
    #pragma unroll
    for (int kp = 0; kp < 8; ++kp) {
      half4 ah = *(const half4*)&hls[w][c][kp*16 + 4*g];
      z0 = mfma16(ah, *(const half4*)(Pm + PACK_W2 + ((0*8+kp)*64+l)*4), z0);
      z1 = mfma16(ah, *(const half4*)(Pm + PACK_W2 + ((1*8+kp)*64+l)*4), z1);
    }
    float b2c0 = b2f[c], b2c1 = b2f[c+16];
    float g2c0 = g2v[c], g2c1 = g2v[c+16], bt0 = b2v[c], bt1 = b2v[c+16];
    float xn0[4], xn1[4];
    #pragma unroll
    for (int reg = 0; reg < 4; ++reg) {
      float u0 = z0[reg] + b2c0 + y0[reg];
      float u1 = z1[reg] + b2c1 + y1[reg];
      float s1 = u0 + u1;
      float s2 = u0*u0 + u1*u1;
      s1 += __shfl_xor(s1, 1); s1 += __shfl_xor(s1, 2);
      s1 += __shfl_xor(s1, 4); s1 += __shfl_xor(s1, 8);
      s2 += __shfl_xor(s2, 1); s2 += __shfl_xor(s2, 2);
      s2 += __shfl_xor(s2, 4); s2 += __shfl_xor(s2, 8);
      float m = s1*(1.f/32.f);
      float rv = rsqrtf(s2*(1.f/32.f) - m*m + 1e-5f);
      xn0[reg] = (u0-m)*rv*g2c0 + bt0;
      xn1[reg] = (u1-m)*rv*g2c1 + bt1;
    }
    #pragma unroll
    for (int reg = 0; reg < 4; ++reg) {
      size_t Rd = (size_t)(r0 + 4*g + reg);
      xf[Rd*32 + c]      = xn0[reg];
      xf[Rd*32 + c + 16] = xn1[reg];
    }
    if (DO_QKV) {
      #pragma unroll
      for (int reg = 0; reg < 4; ++reg) {
        yls[w][4*g+reg][c]      = (_Float16)xn0[reg];
        yls[w][4*g+reg][c + 16] = (_Float16)xn1[reg];
      }
      ax_lo = *(const half4*)&yls[w][c][4*g];
      ax_hi = *(const half4*)&yls[w][c][16 + 4*g];
    }
  } else if (DO_QKV) {
    ax_lo = *(const half4*)(xh + (size_t)(r0 + c)*32 + 4*g);
    ax_hi = *(const half4*)(xh + (size_t)(r0 + c)*32 + 16 + 4*g);
  }

  if (DO_QKV) {
    #pragma unroll
    for (int t = 0; t < 6; ++t) {
      float4v qc = mfma16(ax_lo, *(const half4*)(Pq + PACK_WQ + ((t*2+0)*64+l)*4), zc);
      qc = mfma16(ax_hi, *(const half4*)(Pq + PACK_WQ + ((t*2+1)*64+l)*4), qc);
      const int colg = t*16 + c;
      float bb = bqkv[colg] * ((t < 2) ? QSCALE : 1.f);
      const int sec = t >> 1;
      const int hh = (colg & 31) >> 3, dd = colg & 7;
      #pragma unroll
      for (int reg = 0; reg < 4; ++reg) {
        unsigned Rd = (unsigned)(r0 + 4*g + reg);
        unsigned bI = Rd / 652u;
        unsigned p  = Rd - bI*652u;
        _Float16 v = (_Float16)(qc[reg] + bb);
        if (sec == 0)      qkh[((size_t)(bI*4+hh)*NPOS + p)*8 + dd] = v;
        else if (sec == 1) kbh[((size_t)(bI*4+hh)*NPOS + p)*8 + dd] = v;
        else               vth[((size_t)(bI*4+hh)*8 + dd)*NPOS + p] = v;
      }
    }
  }
}

// ------------------------------------------------------------------ attn ----
// half-major remap: bh = blk & 511, half = blk >> 9 (same-XCD K/V pairs).
#define VSTR 670
__global__ __launch_bounds__(512) void attn_kernel(
    const _Float16* __restrict__ qkh, const _Float16* __restrict__ kbh,
    const _Float16* __restrict__ vth, _Float16* __restrict__ oh)
{
  __shared__ _Float16 Klds[656*8];       // 10.5 KB
  __shared__ _Float16 VTlds[16*VSTR];    // 20.9 KB
  int blk = blockIdx.x;
  int bh = blk & 511, half = blk >> 9;
  int b = bh >> 2, h = bh & 3;
  int tid = threadIdx.x;
  const half4 z4 = {0,0,0,0};
  const half4 o4 = {(_Float16)1.f,(_Float16)1.f,(_Float16)1.f,(_Float16)1.f};
  for (int r = tid; r < 656; r += 512) {
    half8 kv = {0,0,0,0,0,0,0,0};
    if (r < NPOS) kv = *(const half8*)(kbh + ((size_t)bh*NPOS + r)*8);
    *(half8*)(Klds + r*8) = kv;
  }
  for (int i = tid; i < 16*167; i += 512) {
    int d = i / 167, kc = (i % 167)*4;
    half4 v = z4;
    if (kc < 652) {
      if (d < 8)       v = *(const half4*)(vth + ((size_t)bh*8 + d)*NPOS + kc);
      else if (d == 8) v = o4;
    }
    *(half4*)(VTlds + d*VSTR + kc) = v;
  }
  __syncthreads();

  int wave = tid >> 6, lane = tid & 63;
  int q16 = lane & 15;
  int kg  = lane >> 4;
  const int denl = (lane & 48) | 8;
  const float4v zc = {0.f,0.f,0.f,0.f};
  const int lo = half ? 21 : 0;
  const int span = half ? 20 : 21;

  // ---- sweep 1: dual chain
  {
    const int qtA = lo + wave, qtB = lo + wave + 8;
    int qrcA = qtA*16 + q16;
    int qrowB = qtB*16 + q16;
    int qrcB = qrowB < NPOS ? qrowB : NPOS-1;
    half4 qfA = z4, qfB = z4;
    if (kg < 2) {
      qfA = *(const half4*)(qkh + ((size_t)bh*NPOS + qrcA)*8 + kg*4);
      qfB = *(const half4*)(qkh + ((size_t)bh*NPOS + qrcB)*8 + kg*4);
    }
    float4v oA = zc, oB = zc;
    for (int kt = 0; kt < 41; ++kt) {
      half4 kf = z4;
      if (kg < 2)
        kf = *(const half4*)(Klds + (kt*16 + q16)*8 + kg*4);
      half4 vf = *(const half4*)(VTlds + q16*VSTR + kt*16 + (kg << 2));
      float4v sA = __builtin_amdgcn_mfma_f32_16x16x16f16(kf, qfA, zc, 0, 0, 0);
      float4v sB = __builtin_amdgcn_mfma_f32_16x16x16f16(kf, qfB, zc, 0, 0, 0);
      half4 pfA, pfB;
      pfA[0] = (_Float16)__builtin_amdgcn_exp2f(sA[0]);
      pfA[1] = (_Float16)__builtin_amdgcn_exp2f(sA[1]);
      pfA[2] = (_Float16)__builtin_amdgcn_exp2f(sA[2]);
      pfA[3] = (_Float16)__builtin_amdgcn_exp2f(sA[3]);
      pfB[0] = (_Float16)__builtin_amdgcn_exp2f(sB[0]);
      pfB[1] = (_Float16)__builtin_amdgcn_exp2f(sB[1]);
      pfB[2] = (_Float16)__builtin_amdgcn_exp2f(sB[2]);
      pfB[3] = (_Float16)__builtin_amdgcn_exp2f(sB[3]);
      oA = __builtin_amdgcn_mfma_f32_16x16x16f16(pfA, vf, oA, 0, 0, 0);
      oB = __builtin_amdgcn_mfma_f32_16x16x16f16(pfB, vf, oB, 0, 0, 0);
    }
    float dqA[4], dqB[4];
    #pragma unroll
    for (int reg = 0; reg < 4; ++reg) {
      dqA[reg] = __shfl(oA[reg], denl);
      dqB[reg] = __shfl(oB[reg], denl);
    }
    if (q16 < 8) {
      #pragma unroll
      for (int reg = 0; reg < 4; ++reg) {
        int qoA = qtA*16 + 4*kg + reg;
        oh[((size_t)(b*NPOS + qoA))*32 + h*8 + q16] = (_Float16)(oA[reg] / dqA[reg]);
        int qoB = qtB*16 + 4*kg + reg;
        if (qoB < NPOS)
          oh[((size_t)(b*NPOS + qoB))*32 + h*8 + q16] = (_Float16)(oB[reg] / dqB[reg]);
      }
    }
  }
  // ---- sweep 2: single-chain tail
  if (wave < span - 16) {
    const int qt = lo + 16 + wave;
    int qrow = qt*16 + q16;
    int qrc = qrow < NPOS ? qrow : NPOS-1;
    half4 qf = z4;
    if (kg < 2)
      qf = *(const half4*)(qkh + ((size_t)bh*NPOS + qrc)*8 + kg*4);
    float4v o = zc;
    for (int kt = 0; kt < 41; ++kt) {
      half4 kf = z4;
      if (kg < 2)
        kf = *(const half4*)(Klds + (kt*16 + q16)*8 + kg*4);
      half4 vf = *(const half4*)(VTlds + q16*VSTR + kt*16 + (kg << 2));
      float4v s = __builtin_amdgcn_mfma_f32_16x16x16f16(kf, qf, zc, 0, 0, 0);
      half4 pf;
      pf[0] = (_Float16)__builtin_amdgcn_exp2f(s[0]);
      pf[1] = (_Float16)__builtin_amdgcn_exp2f(s[1]);
      pf[2] = (_Float16)__builtin_amdgcn_exp2f(s[2]);
      pf[3] = (_Float16)__builtin_amdgcn_exp2f(s[3]);
      o = __builtin_amdgcn_mfma_f32_16x16x16f16(pf, vf, o, 0, 0, 0);
    }
    float dq[4];
    #pragma unroll
    for (int reg = 0; reg < 4; ++reg)
      dq[reg] = __shfl(o[reg], denl);
    if (q16 < 8) {
      #pragma unroll
      for (int reg = 0; reg < 4; ++reg) {
        int qo = qt*16 + 4*kg + reg;
        if (qo < NPOS)
          oh[((size_t)(b*NPOS + qo))*32 + h*8 + q16] = (_Float16)(o[reg] / dq[reg]);
      }
    }
  }
}

// --------------------------------------------------------------- readout ----
__global__ __launch_bounds__(256) void readout_kernel(
    const float* __restrict__ x,
    const float* __restrict__ Wtraj, const float* __restrict__ btraj,
    const float* __restrict__ Wint, const float* __restrict__ bint,
    float* __restrict__ dout)
{
  int idx = blockIdx.x*256 + threadIdx.x;
  if (idx >= NB*NVEH) return;
  int b = idx >> 6, n = idx & 63;
  int z = n >> 4, v = n & 15;
  int base = 4 + z*ZSTRIDE + 2 + v*10;
  float acc[16];
  #pragma unroll
  for (int i = 0; i < 16; ++i) acc[i] = btraj[i];
  #pragma unroll
  for (int t = 0; t < 4; ++t) {
    const float* xr = x + ((size_t)(b*NPOS + base + 6 + t))*32;
    #pragma unroll
    for (int k = 0; k < 32; ++k) {
      float xv = xr[k];
      const float* wr = Wtraj + (t*32 + k)*16;
      #pragma unroll
      for (int i = 0; i < 16; ++i) acc[i] += xv*wr[i];
    }
  }
  float* to = dout + (size_t)idx*16;
  #pragma unroll
  for (int i = 0; i < 16; ++i) to[i] = acc[i];
  float ai[8];
  #pragma unroll
  for (int j = 0; j < 8; ++j) ai[j] = bint[j];
  #pragma unroll
  for (int t = 0; t < 2; ++t) {
    const float* xr = x + ((size_t)(b*NPOS + base + 4 + t))*32;
    #pragma unroll
    for (int k = 0; k < 32; ++k) {
      float xv = xr[k];
      const float* wr = Wint + (t*32 + k)*8;
      #pragma unroll
      for (int j = 0; j < 8; ++j) ai[j] += xv*wr[j];
    }
  }
  float* io = dout + 131072 + (size_t)idx*8;
  #pragma unroll
  for (int j = 0; j < 8; ++j) io[j] = ai[j];
}

// ---------------------------------------------------------------- launch ----
extern "C" void kernel_launch(void* const* d_in, const int* in_sizes, int n_in,
                              void* d_out, int out_size, void* d_ws, size_t ws_size,
                              hipStream_t stream)
{
  const float* states  = (const float*)d_in[0];
  const float* road_ctx= (const float*)d_in[1];
  const float* pos_emb = (const float*)d_in[2];
  const float* Wp    = (const float*)d_in[4];  const float* bp    = (const float*)d_in[5];
  const float* Wv    = (const float*)d_in[6];  const float* bv    = (const float*)d_in[7];
  const float* Wh    = (const float*)d_in[8];  const float* bh    = (const float*)d_in[9];
  const float* Wc    = (const float*)d_in[10]; const float* bc    = (const float*)d_in[11];
  const float* Wflow = (const float*)d_in[12]; const float* bflow = (const float*)d_in[13];
  const float* Wsig  = (const float*)d_in[14]; const float* bsig  = (const float*)d_in[15];
  const float* Wtraj = (const float*)d_in[16]; const float* btraj = (const float*)d_in[17];
  const float* Wint  = (const float*)d_in[18]; const float* bint  = (const float*)d_in[19];
  const float* Wqkv  = (const float*)d_in[20]; const float* bqkv  = (const float*)d_in[21];
  const float* Wo    = (const float*)d_in[22]; const float* bo    = (const float*)d_in[23];
  const float* g1    = (const float*)d_in[24]; const float* b1ln  = (const float*)d_in[25];
  const float* W1    = (const float*)d_in[26]; const float* b1    = (const float*)d_in[27];
  const float* W2    = (const float*)d_in[28]; const float* b2    = (const float*)d_in[29];
  const float* g2    = (const float*)d_in[30]; const float* b2ln  = (const float*)d_in[31];

  // workspace layout
  float*     xf  = (float*)d_ws;                           // 10.7 MB fp32
  _Float16*  oh  = (_Float16*)(xf + (size_t)MROWS*32);     // 5.3 MB f16
  _Float16*  xh  = oh  + (size_t)MROWS*32;                 // 5.3 MB f16
  _Float16*  qkh = xh  + (size_t)MROWS*32;                 // 5.3 MB
  _Float16*  kbh = qkh + (size_t)512*NPOS*8;               // 5.3 MB
  _Float16*  vth = kbh + (size_t)512*NPOS*8;               // 5.3 MB
  _Float16*  P   = vth + (size_t)512*NPOS*8;               // 48 KB packed W

  canvas_kernel<<<NB*8, 256, 0, stream>>>(states, road_ctx, pos_emb,
      Wp, bp, Wv, bv, Wh, bh, Wc, bc, Wflow, bflow, Wsig, bsig, xf, xh);

  pack_kernel<<<2, 64, 0, stream>>>(Wqkv, Wo, W1, W2, P);

  const int eBlocks = MROWS/64;   // 1304

  // layer 0 qkv (from canvas xh; qkv weights layer 0)
  engine_kernel<false,true><<<eBlocks, 256, 0, stream>>>(
      nullptr, xh, xf, nullptr, P,
      nullptr, nullptr, nullptr, nullptr, nullptr, nullptr, nullptr,
      bqkv, qkh, kbh, vth);

  attn_kernel<<<NB*NH*2, 512, 0, stream>>>(qkh, kbh, vth, oh);

  // layer 0 proj+LN+FFN+LN (Pm = layer 0) fused with layer 1 qkv (Pq = layer 1)
  engine_kernel<true,true><<<eBlocks, 256, 0, stream>>>(
      oh, nullptr, xf, P, P + PACK_LAYER,
      bo, g1, b1ln, b1, b2, g2, b2ln,
      bqkv + 96, qkh, kbh, vth);

  attn_kernel<<<NB*NH*2, 512, 0, stream>>>(qkh, kbh, vth, oh);

  // layer 1 proj+LN+FFN+LN (Pm = layer 1)
  engine_kernel<true,false><<<eBlocks, 256, 0, stream>>>(
      oh, nullptr, xf, P + PACK_LAYER, nullptr,
      bo + 32, g1 + 32, b1ln + 32, b1 + 128, b2 + 32, g2 + 32, b2ln + 32,
      nullptr, nullptr, nullptr, nullptr);

  readout_kernel<<<(NB*NVEH + 255)/256, 256, 0, stream>>>(
      xf, Wtraj, btraj, Wint, bint, (float*)d_out);
}